// Round 8
// baseline (1089.041 us; speedup 1.0000x reference)
//
#include <hip/hip_runtime.h>
#include <cstdint>
#include <cmath>

// ---------------- constants ----------------
namespace {
constexpr int BATCH = 4;
constexpr int CIN   = 512;
constexpr int CMID  = 512;
constexpr int HSZ   = 64, WSZ = 64, HWP = 4096;
constexpr int NA    = 36864;          // HW * 9 anchors
constexpr int NIN_  = 6000;
constexpr int NOUT2 = 300;
constexpr int NW    = 94;             // ceil(6000/64) u64 words per bitmask row

// d_out layout (float offsets)
constexpr size_t O_SC  = 0;           // rpn_scores (4,36864,2)
constexpr size_t O_LC  = 294912;      // rpn_locs   (4,36864,4)
constexpr size_t O_ROI = 884736;      // rois       (1200,4)
constexpr size_t O_IDX = 889536;      // roi_indices(1200)
constexpr size_t O_ANC = 890736;      // anchors    (36864,4)

// d_ws layout (float offsets).
// Aliasing rules:
//  - region [0, 8388608) is h; buffers there may be WRITTEN only after k2 (last h reader).
//  - region [8388608, 10747904) is gw2 (W fragments); DEAD after k1. gh0/gcnt live there
//    and are zeroed inside k2 (k2 never touches this region; k1 has completed) — this is
//    NOT the round-4 race (that zeroed h-aliased memory while k2 blocks still read h).
constexpr size_t W_H    = 0;          // 8388608 floats (conv hidden, NCHW)
constexpr size_t W_WHI  = 8388608;    // 4718592 f16 W fragments [chunk][kk][cg][wc][nt][hl][lane][8]
constexpr size_t W_GH0  = 8388608;    // 16384 ints level-0 histogram (aliases gw2, dead post-k1)
constexpr size_t W_GCNT = 8404992;    // 4 ints compact counter (aliases gw2)
constexpr size_t W_XSP  = 10747904;   // 16777216 f16 X split [b][chunk][px][ciq(hi4,lo4)]
constexpr size_t W_END_PS = 19136512; // high-water (floats) when x-split enabled
constexpr size_t W_R4   = 0;          // 589824  rois per anchor (aliases h)
constexpr size_t W_SK   = 589824;     // 147456  score keys (fg or -inf) -> ends 737280
constexpr size_t W_CT0  = 786496;     // 4 ints cut0 | 4 ints prev0
constexpr size_t W_CKEY = 901184;     // 147456 u64 keys (8B aligned)
constexpr size_t W_RS   = 1196096;    // 96000  sorted rois (4,6000,4)
constexpr size_t W_VS   = 1292096;    // 24000 ints sorted validity
constexpr size_t W_MAT  = 1316096;    // 4*6000*94 u64 (suppression bits)
} // namespace

typedef _Float16 f16;
typedef __attribute__((ext_vector_type(4))) _Float16 f16x4;
typedef __attribute__((ext_vector_type(8))) _Float16 f16x8;
typedef __attribute__((ext_vector_type(4))) float f32x4;

// ---------------- K0w: split conv_w*64 into f16 hi/lo, emit per-wave FRAGMENT layout ----
__global__ __launch_bounds__(256) void k0w(const float* __restrict__ w,
                                           f16* __restrict__ gw2) {
    int g = blockIdx.x * 256 + threadIdx.x;   // 589824 groups of 8 f16
    int lane = g & 63;
    int t1 = g >> 6;
    int hl = t1 & 1;
    int nt = (t1 >> 1) & 3;
    int wc = (t1 >> 3) & 1;
    int cg = (t1 >> 4) & 3;
    int ck = t1 >> 6;                 // 0..143
    int kk = ck % 9;
    int chunk = ck / 9;
    int co  = cg * 128 + wc * 64 + nt * 16 + (lane & 15);
    int ci0 = chunk * 32 + (lane >> 4) * 8;
    f16x8 o;
#pragma unroll
    for (int e = 0; e < 8; ++e) {
        float f = w[((size_t)co * CIN + ci0 + e) * 9 + kk] * 64.0f;
        f16 hv = (f16)f;
        o[e] = hl ? (f16)((f - (float)hv) * 2048.0f) : hv;
    }
    *(f16x8*)&gw2[(size_t)g * 8] = o;
}

// ---------------- K0x: pre-split X into f16 hi/lo, layout [b][chunk][px][ciq(hi4,lo4)] ----
__global__ __launch_bounds__(256) void k0x(const float* __restrict__ x,
                                           f16* __restrict__ xsp) {
    const int pt = blockIdx.x, ch = blockIdx.y, b = blockIdx.z, t = threadIdx.x;
    __shared__ float ld[32 * 261];   // [ci][px] pad 261 (odd) -> conflict-free column reads
    const int px0 = pt * 256;
    const int lpx = (t & 63) * 4, lc0 = t >> 6;
#pragma unroll
    for (int r = 0; r < 8; ++r) {
        int ci = r * 4 + lc0;
        float4 v = *(const float4*)&x[((size_t)(b * 512 + ch * 32 + ci)) * 4096 + px0 + lpx];
        float* d = &ld[ci * 261 + lpx];
        d[0] = v.x; d[1] = v.y; d[2] = v.z; d[3] = v.w;
    }
    __syncthreads();
    size_t ob = ((size_t)(b * 16 + ch) * 4096 + px0 + t) * 64;
#pragma unroll
    for (int cqx = 0; cqx < 8; ++cqx) {
        f16x8 o;
#pragma unroll
        for (int i = 0; i < 4; ++i) {
            float f = ld[(cqx * 4 + i) * 261 + t];
            f16 hf = (f16)f;
            o[i]     = hf;
            o[4 + i] = (f16)((f - (float)hf) * 2048.0f);
        }
        *(f16x8*)&xsp[ob + cqx * 8] = o;
    }
}

// ---------------- K1: 3x3 conv + bias + ReLU via f16-split MFMA (3 products) ----------
// Round-5 proven version (212 us). The T14 register-prefetch variant REGRESSED
// (FETCH +30%: early-issued xsp loads evicted the shared gw2 slices from L2) — reverted.
template <bool PS>
__global__ __launch_bounds__(256, 2) void k1_mfma(const float* __restrict__ x,
                                                  const f16* __restrict__ xsp,
                                                  const f16* __restrict__ gw2,
                                                  const float* __restrict__ bias,
                                                  float* __restrict__ h) {
    const int pt = blockIdx.x, cg = blockIdx.y, b = blockIdx.z;
    const int y0 = pt * 2, co0 = cg * 128;
    const int t = threadIdx.x;
    const int wave = t >> 6, lane = t & 63;
    const int wp = wave >> 1, wc = wave & 1;   // px-half, co-half
    const int m = lane & 15, q = lane >> 4;

    __shared__ __align__(16) f16 xs[2][4 * 66 * 40];

    f32x4 acc1[2][2][4], acc2[2][2][4];
#pragma unroll
    for (int r = 0; r < 2; ++r)
#pragma unroll
        for (int j = 0; j < 2; ++j)
#pragma unroll
            for (int n = 0; n < 4; ++n) { acc1[r][j][n] = (f32x4)0.0f; acc2[r][j][n] = (f32x4)0.0f; }

    const int cq = t & 7, srow = (t >> 3) & 3, cseg = t >> 5;
    const int gy = y0 - 1 + srow;
    const bool yok = (gy >= 0 && gy < HSZ);

    if (t < 128) {   // zero borders (cols 0 and 65) of both planes, once
        int buf = t >> 6, rr = (t >> 4) & 3, cc = ((t >> 3) & 1) ? 65 : 0, cq2 = t & 7;
        f16x4 z = (f16x4)(f16)0.0f;
        *(f16x4*)&xs[buf][(rr * 66 + cc) * 40 + cq2 * 4] = z;
    }

    const size_t wlanebase = (size_t)(cg * 2 + wc) * 4096 + (size_t)lane * 8;

    for (int chunk = 0; chunk < 16; ++chunk) {
        __syncthreads();   // all waves done reading previous chunk's xs
        if (PS) {
            const f16* xb = xsp + (((size_t)(b * 16 + chunk) * 4096 + (size_t)(yok ? gy : 0) * 64) * 64);
#pragma unroll
            for (int jj = 0; jj < 8; ++jj) {
                int c = (jj + cq) & 7;
                int col = cseg * 8 + c + 1;
                f16x8 v = (f16x8)(f16)0.0f;
                if (yok) v = *(const f16x8*)&xb[(size_t)(cseg * 8 + c) * 64 + cq * 8];
                int base = (srow * 66 + col) * 40 + cq * 4;
                *(f16x4*)&xs[0][base] = __builtin_shufflevector(v, v, 0, 1, 2, 3);
                *(f16x4*)&xs[1][base] = __builtin_shufflevector(v, v, 4, 5, 6, 7);
            }
        } else {
            float vbuf[4][8];
            const float* xp = x + ((size_t)(b * CIN + chunk * 32 + cq * 4)) * HWP + gy * WSZ + cseg * 8;
#pragma unroll
            for (int i = 0; i < 4; ++i) {
                if (yok) {
                    float4 u0 = *(const float4*)(xp + (size_t)i * HWP);
                    float4 u1 = *(const float4*)(xp + (size_t)i * HWP + 4);
                    vbuf[i][0] = u0.x; vbuf[i][1] = u0.y; vbuf[i][2] = u0.z; vbuf[i][3] = u0.w;
                    vbuf[i][4] = u1.x; vbuf[i][5] = u1.y; vbuf[i][6] = u1.z; vbuf[i][7] = u1.w;
                } else {
#pragma unroll
                    for (int jj = 0; jj < 8; ++jj) vbuf[i][jj] = 0.0f;
                }
            }
#pragma unroll
            for (int jj = 0; jj < 8; ++jj) {
                int c = (jj + cq) & 7;
                int col = cseg * 8 + c + 1;
                f16x4 hv, lv;
#pragma unroll
                for (int i = 0; i < 4; ++i) {
                    float f = vbuf[i][c];
                    f16 hf = (f16)f;
                    hv[i] = hf;
                    lv[i] = (f16)((f - (float)hf) * 2048.0f);
                }
                int base = (srow * 66 + col) * 40 + cq * 4;
                *(f16x4*)&xs[0][base] = hv;
                *(f16x4*)&xs[1][base] = lv;
            }
        }
        __syncthreads();   // xs ready

        const f16* wck = gw2 + (size_t)chunk * (9 * 32768) + wlanebase;
#pragma unroll
        for (int kk = 0; kk < 9; ++kk) {
            const int ky = (kk >= 6) ? 2 : (kk >= 3) ? 1 : 0;
            const int kx = kk - ky * 3;
            const f16* wptr = wck + (size_t)kk * 32768;
            f16x8 bh[4], bl[4];
#pragma unroll
            for (int nt = 0; nt < 4; ++nt) {
                bh[nt] = *(const f16x8*)&wptr[nt * 1024];
                bl[nt] = *(const f16x8*)&wptr[nt * 1024 + 512];
            }
            f16x8 ah[2][2], al[2][2];
#pragma unroll
            for (int r = 0; r < 2; ++r)
#pragma unroll
                for (int j = 0; j < 2; ++j) {
                    int off = ((r + ky) * 66 + (wp * 2 + j) * 16 + m + kx) * 40 + q * 8;
                    ah[r][j] = *(const f16x8*)&xs[0][off];
                    al[r][j] = *(const f16x8*)&xs[1][off];
                }
#pragma unroll
            for (int r = 0; r < 2; ++r)
#pragma unroll
                for (int j = 0; j < 2; ++j)
#pragma unroll
                    for (int nt = 0; nt < 4; ++nt) {
                        acc1[r][j][nt] = __builtin_amdgcn_mfma_f32_16x16x32_f16(ah[r][j], bh[nt], acc1[r][j][nt], 0, 0, 0);
                        acc2[r][j][nt] = __builtin_amdgcn_mfma_f32_16x16x32_f16(ah[r][j], bl[nt], acc2[r][j][nt], 0, 0, 0);
                        acc2[r][j][nt] = __builtin_amdgcn_mfma_f32_16x16x32_f16(al[r][j], bh[nt], acc2[r][j][nt], 0, 0, 0);
                    }
        }
    }

#pragma unroll
    for (int r = 0; r < 2; ++r) {
        const int y = y0 + r;
#pragma unroll
        for (int nt = 0; nt < 4; ++nt) {
            const int co = co0 + wc * 64 + nt * 16 + m;
            const float bv = bias[co];
            size_t rowbase = ((size_t)(b * CMID + co)) * HWP + y * WSZ;
#pragma unroll
            for (int j = 0; j < 2; ++j) {
                float4 o;
                o.x = fmaxf((acc1[r][j][nt][0] + acc2[r][j][nt][0] * (1.0f / 2048.0f)) * (1.0f / 64.0f) + bv, 0.0f);
                o.y = fmaxf((acc1[r][j][nt][1] + acc2[r][j][nt][1] * (1.0f / 2048.0f)) * (1.0f / 64.0f) + bv, 0.0f);
                o.z = fmaxf((acc1[r][j][nt][2] + acc2[r][j][nt][2] * (1.0f / 2048.0f)) * (1.0f / 64.0f) + bv, 0.0f);
                o.w = fmaxf((acc1[r][j][nt][3] + acc2[r][j][nt][3] * (1.0f / 2048.0f)) * (1.0f / 64.0f) + bv, 0.0f);
                *(float4*)&h[rowbase + (wp * 2 + j) * 16 + q * 4] = o;
            }
        }
    }
}

// ---------------- K2: 1x1 convs (score 18 + loc 36) -> d_out; zeros gh0/gcnt ----------
// gh0/gcnt alias the gw2 region, which is DEAD after k1 and untouched by k2's own
// reads/writes — zeroing here is race-free (unlike round-4's h-aliased zeroing).
__global__ __launch_bounds__(256) void k2_conv1(const float* __restrict__ h,
                                                const float* __restrict__ sw,
                                                const float* __restrict__ sb,
                                                const float* __restrict__ lw,
                                                const float* __restrict__ lb,
                                                float* __restrict__ out,
                                                int* __restrict__ gz,
                                                int* __restrict__ gcnt) {
    const int y = blockIdx.x;
    const int b = blockIdx.y;
    const int t = threadIdx.x;
    {
        int fb = (blockIdx.y * 64 + blockIdx.x) * 256 + t;   // 65536 threads
        if (fb < 4096 * BATCH) gz[fb] = 0;
        if (fb < BATCH) gcnt[fb] = 0;
    }
    const int c4  = (t & 15) * 4;
    const int px4 = (t >> 4) * 4;
    __shared__ __align__(16) float hs[1024];
    __shared__ __align__(16) float wsm[16 * 68];

    float acc[4][4];
#pragma unroll
    for (int i = 0; i < 4; ++i)
#pragma unroll
        for (int j = 0; j < 4; ++j) acc[i][j] = 0.f;

    const int s_px = (t & 15) * 4;
    const int s_ci = t >> 4;
    for (int ci0 = 0; ci0 < CMID; ci0 += 16) {
        *(float4*)&hs[s_ci * 64 + s_px] =
            *(const float4*)&h[((size_t)(b * CMID + ci0 + s_ci)) * HWP + y * 64 + s_px];
#pragma unroll
        for (int k = 0; k < 4; ++k) {
            int idx = k * 256 + t;
            int ci = idx & 15, c = idx >> 4;
            float v = 0.f;
            if (c < 18) v = sw[c * 512 + ci0 + ci];
            else if (c < 54) v = lw[(c - 18) * 512 + ci0 + ci];
            wsm[ci * 68 + c] = v;
        }
        __syncthreads();
#pragma unroll
        for (int ci = 0; ci < 16; ++ci) {
            float4 hv = *(const float4*)&hs[ci * 64 + px4];
            float4 wv = *(const float4*)&wsm[ci * 68 + c4];
            acc[0][0] = fmaf(wv.x, hv.x, acc[0][0]);
            acc[0][1] = fmaf(wv.x, hv.y, acc[0][1]);
            acc[0][2] = fmaf(wv.x, hv.z, acc[0][2]);
            acc[0][3] = fmaf(wv.x, hv.w, acc[0][3]);
            acc[1][0] = fmaf(wv.y, hv.x, acc[1][0]);
            acc[1][1] = fmaf(wv.y, hv.y, acc[1][1]);
            acc[1][2] = fmaf(wv.y, hv.z, acc[1][2]);
            acc[1][3] = fmaf(wv.y, hv.w, acc[1][3]);
            acc[2][0] = fmaf(wv.z, hv.x, acc[2][0]);
            acc[2][1] = fmaf(wv.z, hv.y, acc[2][1]);
            acc[2][2] = fmaf(wv.z, hv.z, acc[2][2]);
            acc[2][3] = fmaf(wv.z, hv.w, acc[2][3]);
            acc[3][0] = fmaf(wv.w, hv.x, acc[3][0]);
            acc[3][1] = fmaf(wv.w, hv.y, acc[3][1]);
            acc[3][2] = fmaf(wv.w, hv.z, acc[3][2]);
            acc[3][3] = fmaf(wv.w, hv.w, acc[3][3]);
        }
        __syncthreads();
    }

#pragma unroll
    for (int cc = 0; cc < 4; ++cc) {
        int c = c4 + cc;
        if (c >= 54) break;
        float bv = (c < 18) ? sb[c] : lb[c - 18];
#pragma unroll
        for (int pp = 0; pp < 4; ++pp) {
            int px = y * 64 + px4 + pp;
            float v = acc[cc][pp] + bv;
            if (c < 18)
                out[O_SC + (size_t)b * 73728 + (size_t)px * 18 + c] = v;
            else
                out[O_LC + (size_t)b * 147456 + (size_t)px * 36 + (c - 18)] = v;
        }
    }
}

// ---------------- K3: anchors + softmax-fg + loc2bbox + clip + level-0 histogram -------
__global__ __launch_bounds__(256) void k3_prop(float* __restrict__ out,
                                               float* __restrict__ rois4,
                                               float* __restrict__ skey,
                                               int* __restrict__ gh0) {
    const int t = threadIdx.x;
    const int p = blockIdx.x * 256 + t;
    const int b = blockIdx.y;
    __shared__ int lh[4096];
    for (int k = t; k < 4096; k += 256) lh[k] = 0;
    __syncthreads();
    const int px = p / 9;
    const int a  = p - px * 9;
    const int yy = px >> 6, xx = px & 63;
    const int ri = a / 3, si = a - ri * 3;
    const double rat[3] = {0.5, 1.0, 2.0};
    const double scl[3] = {8.0, 16.0, 32.0};
    double hhd = 16.0 * scl[si] * sqrt(rat[ri]);
    double wwd = 16.0 * scl[si] * sqrt(1.0 / rat[ri]);
    float a0 = (float)(8.0 - hhd / 2.0), a1 = (float)(8.0 - wwd / 2.0);
    float a2 = (float)(8.0 + hhd / 2.0), a3 = (float)(8.0 + wwd / 2.0);
    float sy = (float)(yy * 16), sx = (float)(xx * 16);
    float A0 = sy + a0, A1 = sx + a1, A2 = sy + a2, A3 = sx + a3;
    if (b == 0) {
        float4 av; av.x = A0; av.y = A1; av.z = A2; av.w = A3;
        *(float4*)&out[O_ANC + (size_t)p * 4] = av;
    }
    const float* sc = out + O_SC + (size_t)b * 73728 + (size_t)px * 18 + a * 2;
    float s0 = sc[0], s1 = sc[1];
    float mm = fmaxf(s0, s1);
    float e0 = expf(s0 - mm), e1 = expf(s1 - mm);
    float fg = e1 / (e0 + e1);
    const float* lc = out + O_LC + (size_t)b * 147456 + (size_t)px * 36 + a * 4;
    float dy = lc[0], dxv = lc[1], dh = lc[2], dwv = lc[3];
    float ah = A2 - A0, aw = A3 - A1;
    float cy = A0 + 0.5f * ah, cx = A1 + 0.5f * aw;
    float cty = dy * ah + cy, ctx = dxv * aw + cx;
    float th = expf(dh) * ah, tw = expf(dwv) * aw;
    float ry1 = cty - 0.5f * th, rx1 = ctx - 0.5f * tw;
    float ry2 = cty + 0.5f * th, rx2 = ctx + 0.5f * tw;
    float y1 = fminf(fmaxf(ry1, 0.f), 1024.f);
    float y2 = fminf(fmaxf(ry2, 0.f), 1024.f);
    float x1 = fminf(fmaxf(rx1, 0.f), 1024.f);
    float x2 = fminf(fmaxf(rx2, 0.f), 1024.f);
    bool valid = ((y2 - y1) >= 16.f) && ((x2 - x1) >= 16.f);
    float sk = valid ? fg : -__builtin_inff();
    float4 rv; rv.x = y1; rv.y = x1; rv.z = y2; rv.w = x2;
    *(float4*)&rois4[((size_t)b * NA + p) * 4] = rv;
    skey[(size_t)b * NA + p] = sk;
    // level-0 histogram of the sortable key's top 12 bits
    unsigned uu = __float_as_uint(sk);
    uu = (uu & 0x80000000u) ? ~uu : (uu | 0x80000000u);
    atomicAdd(&lh[uu >> 20], 1);
    __syncthreads();
    for (int k = t; k < 4096; k += 256) {
        int v = lh[k];
        if (v) atomicAdd(&gh0[(size_t)b * 4096 + k], v);
    }
}

// ---------------- K4a: level-0 cut from gh0 (grid=BATCH) ----------------
__global__ __launch_bounds__(256) void k4cut0(const int* __restrict__ gh,
                                              int* __restrict__ cut0,
                                              int* __restrict__ prev0) {
    const int b = blockIdx.x, t = threadIdx.x;
    __shared__ int hh[4096];
    __shared__ int tsum[256];
    __shared__ int s_cut, s_prev;
    for (int k = t; k < 4096; k += 256) hh[k] = gh[(size_t)b * 4096 + k];
    __syncthreads();
    int s = 0;
#pragma unroll
    for (int j = 0; j < 16; ++j) s += hh[t * 16 + j];
    tsum[t] = s;
    __syncthreads();
    if (t == 0) {
        int run = 0;
        for (int tt = 255; tt >= 0; --tt) { int tmp = tsum[tt]; tsum[tt] = run; run += tmp; }
    }
    __syncthreads();
    {
        const int target = NIN_;
        int run = tsum[t];
        for (int v = t * 16 + 15; v >= t * 16; --v) {
            int prev = run;
            run += hh[v];
            if (run >= target && prev < target) { s_cut = v; s_prev = prev; }
        }
    }
    __syncthreads();
    if (t == 0) { cut0[b] = s_cut; prev0[b] = s_prev; }
}

// ---------------- K4e: single-level compaction (grid=(32,BATCH)), block-aggregated ------
// take = (b1 >= cut0): superset of the exact top-6000 (all greater keys also taken, so
// rank-within-taken == global rank). k4d's exact counting-rank handles any C <= NA.
// Also zero-prefills rois_s/valid_s (insurance; consumed only after k4d fills them).
__global__ __launch_bounds__(256) void k4cmp(const float* __restrict__ skey,
                                             const int* __restrict__ cut0,
                                             int* __restrict__ gcnt,
                                             unsigned long long* __restrict__ ckey,
                                             float* __restrict__ rois_s,
                                             int* __restrict__ valid_s) {
    const int b = blockIdx.y, t = threadIdx.x;
    {
        int gid = (blockIdx.y * 32 + blockIdx.x) * 256 + t;   // 0..32767
        if (gid < BATCH * NIN_) valid_s[gid] = 0;
        for (int k = gid; k < BATCH * NIN_ * 4; k += 32768) rois_s[k] = 0.f;
    }
    __shared__ unsigned long long lbuf[1280];
    __shared__ int lcnt, lbase;
    if (t == 0) lcnt = 0;
    __syncthreads();
    const int c1 = cut0[b];
    for (int i = blockIdx.x * 256 + t; i < NA; i += 32 * 256) {
        float sk = skey[(size_t)b * NA + i];
        unsigned u = __float_as_uint(sk);
        u = (u & 0x80000000u) ? ~u : (u | 0x80000000u);
        if ((int)(u >> 20) >= c1) {
            int lp = atomicAdd(&lcnt, 1);
            lbuf[lp] = ((unsigned long long)u << 16) | (unsigned long long)(36863 - i);
        }
    }
    __syncthreads();
    if (t == 0) lbase = atomicAdd(gcnt + b, lcnt);
    __syncthreads();
    const int n = lcnt, base = lbase;
    for (int k = t; k < n; k += 256) ckey[(size_t)b * NA + base + k] = lbuf[k];
}

// ---------------- K4d: counting-rank over compacted keys, emit top-6000 ------
__global__ __launch_bounds__(256) void k4d_rank(const int* __restrict__ cnt,
                                                const unsigned long long* __restrict__ ckey,
                                                const float* __restrict__ rois4,
                                                float* __restrict__ rois_s,
                                                int* __restrict__ valid_s) {
    const int b = blockIdx.y;
    const int C = cnt[b];
    if (blockIdx.x * 256 >= C) return;
    const int gi = blockIdx.x * 256 + threadIdx.x;
    const bool act = gi < C;
    const unsigned long long mk = act ? ckey[(size_t)b * NA + gi] : 0ULL;
    __shared__ unsigned long long kl[512];
    int rank = 0;
    for (int c0 = 0; c0 < C; c0 += 512) {
        __syncthreads();
#pragma unroll
        for (int kk = 0; kk < 2; ++kk) {
            int k = threadIdx.x + kk * 256;
            int src = c0 + k;
            kl[k] = (src < C) ? ckey[(size_t)b * NA + src] : 0ULL;
        }
        __syncthreads();
        if (act) {
            int n = min(512, C - c0);
            int j = 0;
            for (; j + 4 <= n; j += 4) {
                rank += (kl[j]     > mk);
                rank += (kl[j + 1] > mk);
                rank += (kl[j + 2] > mk);
                rank += (kl[j + 3] > mk);
            }
            for (; j < n; ++j) rank += (kl[j] > mk);
        }
    }
    if (act && rank < NIN_) {
        int p = 36863 - (int)(mk & 0xFFFFull);
        const float4 bx = *(const float4*)&rois4[((size_t)b * NA + p) * 4];
        *(float4*)&rois_s[((size_t)b * NIN_ + rank) * 4] = bx;
        valid_s[b * NIN_ + rank] = ((unsigned)(mk >> 16) != 0x007FFFFFu) ? 1 : 0;
    }
}

// ---------------- K5a: pairwise suppression bitmask matrix ----------------
__global__ __launch_bounds__(256) void k5_mat(const float* __restrict__ rois_s,
                                              unsigned long long* __restrict__ mat) {
    const int b = blockIdx.y, rb = blockIdx.x;
    const int t = threadIdx.x, wave = t >> 6, lane = t & 63;
    const int i = rb * 64 + lane;
    const bool rowok = (i < NIN_);
    __shared__ float cs[4][5][64];
    const float* bb = rois_s + (size_t)b * NIN_ * 4;

    float r0 = 0, r1 = 0, r2 = 0, r3 = 0, ra = 0;
    if (rowok) {
        float4 v = *(const float4*)&bb[(size_t)i * 4];
        r0 = v.x; r1 = v.y; r2 = v.z; r3 = v.w;
        ra = (v.z - v.x) * (v.w - v.y);
    }
    unsigned long long* mrow = mat + ((size_t)b * NIN_ + (size_t)(rowok ? i : 0)) * NW;

    if (rowok)
        for (int cb = wave; cb < rb; cb += 4) mrow[cb] = 0ull;

    for (int cb = rb + wave; cb < NW; cb += 4) {
        const int j0 = cb * 64;
        const int j  = j0 + lane;
        float4 v;
        if (j < NIN_) v = *(const float4*)&bb[(size_t)j * 4];
        else { v.x = 0; v.y = 0; v.z = 0; v.w = 0; }
        cs[wave][0][lane] = v.x; cs[wave][1][lane] = v.y;
        cs[wave][2][lane] = v.z; cs[wave][3][lane] = v.w;
        cs[wave][4][lane] = (v.z - v.x) * (v.w - v.y);
        unsigned long long wm = 0;
        if (rowok) {
#pragma unroll 8
            for (int k = 0; k < 64; ++k) {
                float yy1 = fmaxf(r0, cs[wave][0][k]), xx1 = fmaxf(r1, cs[wave][1][k]);
                float yy2 = fminf(r2, cs[wave][2][k]), xx2 = fminf(r3, cs[wave][3][k]);
                float inter = fmaxf(yy2 - yy1, 0.f) * fmaxf(xx2 - xx1, 0.f);
                float iou = inter / (ra + cs[wave][4][k] - inter + 1e-9f);
                int jj = j0 + k;
                if ((iou > 0.7f) && (jj > i) && (jj < NIN_)) wm |= (1ull << k);
            }
            mrow[cb] = wm;
        }
    }
}

// ---------------- K5b: serial greedy scan, PAIRED candidate processing (proven r7) ------
__global__ __launch_bounds__(64) void k5_scan(const unsigned long long* __restrict__ mat,
                                              const float* __restrict__ rois_s,
                                              const int* __restrict__ valid_s,
                                              float* __restrict__ out) {
    const int b = blockIdx.x, t = threadIdx.x;
    for (int k = t; k < NOUT2 * 4; k += 64) out[O_ROI + (size_t)b * NOUT2 * 4 + k] = 0.f;
    for (int k = t; k < NOUT2; k += 64) out[O_IDX + (size_t)b * NOUT2 + k] = (float)b;

    unsigned long long A = 0, B = 0;
    for (int w = 0; w < NW; ++w) {
        int i = w * 64 + t;
        int v = (i < NIN_) ? valid_s[b * NIN_ + i] : 0;
        unsigned long long m = __ballot(v == 0);
        if (w < 64) { if (t == w) A = m; }
        else        { if (t == w - 64) B = m; }
    }

    const unsigned long long* mb = mat + (size_t)b * NIN_ * NW;
    const float* bb = rois_s + (size_t)b * NIN_ * 4;
    int kept = 0;
    for (int w = 0; w < NW && kept < NOUT2; ++w) {
        unsigned long long cur = (w < 64) ? __shfl(A, w) : __shfl(B, w - 64);
        unsigned long long avail = ~cur;
        while (avail != 0ull && kept < NOUT2) {
            int b0 = __builtin_ctzll(avail);
            unsigned long long rest = avail & (avail - 1ull);
            const int i0 = w * 64 + b0;
            const unsigned long long* row0 = mb + (size_t)i0 * NW;
            unsigned long long r0A = row0[t];
            unsigned long long r0B = (t < NW - 64) ? row0[64 + t] : 0ull;
            const bool has1 = (rest != 0ull);
            const int b1 = has1 ? __builtin_ctzll(rest) : 0;
            unsigned long long r1A = 0ull, r1B = 0ull;
            if (has1) {
                const unsigned long long* row1 = mb + (size_t)(w * 64 + b1) * NW;
                r1A = row1[t];
                r1B = (t < NW - 64) ? row1[64 + t] : 0ull;
            }
            if (t == 0) {
                float4 bx = *(const float4*)&bb[(size_t)i0 * 4];
                *(float4*)&out[O_ROI + ((size_t)b * NOUT2 + kept) * 4] = bx;
            }
            kept++;
            if (kept >= NOUT2) break;
            A |= r0A; B |= r0B;
            unsigned long long rw0 = (w < 64) ? __shfl(r0A, w) : __shfl(r0B, w - 64);
            avail &= ~rw0;
            avail &= ~(1ull << b0);
            if (has1 && (avail & (1ull << b1))) {
                // b1 survived row0 (and all earlier rows) -> it IS the next kept box;
                // its row is already in registers.
                if (t == 0) {
                    float4 bx = *(const float4*)&bb[(size_t)(w * 64 + b1) * 4];
                    *(float4*)&out[O_ROI + ((size_t)b * NOUT2 + kept) * 4] = bx;
                }
                kept++;
                if (kept >= NOUT2) break;
                A |= r1A; B |= r1B;
                unsigned long long rw1 = (w < 64) ? __shfl(r1A, w) : __shfl(r1B, w - 64);
                avail &= ~rw1;
                avail &= ~(1ull << b1);
            }
        }
    }
}

// ---------------- launch ----------------
extern "C" void kernel_launch(void* const* d_in, const int* in_sizes, int n_in,
                              void* d_out, int out_size, void* d_ws, size_t ws_size,
                              hipStream_t stream) {
    const float* x       = (const float*)d_in[0];
    const float* conv_w  = (const float*)d_in[1];
    const float* conv_b  = (const float*)d_in[2];
    const float* score_w = (const float*)d_in[3];
    const float* score_b = (const float*)d_in[4];
    const float* loc_w   = (const float*)d_in[5];
    const float* loc_b   = (const float*)d_in[6];
    float* out = (float*)d_out;
    float* ws  = (float*)d_ws;

    f16* gw2 = (f16*)(ws + W_WHI);   // 4718592 f16 pre-swizzled W fragments
    f16* xsp = (f16*)(ws + W_XSP);
    int* gh0  = (int*)(ws + W_GH0);   // aliases gw2 (dead after k1); zeroed in k2
    int* gcnt = (int*)(ws + W_GCNT);  // aliases gw2
    int* ct0  = (int*)(ws + W_CT0);
    int* pv0  = ct0 + BATCH;
    unsigned long long* ckey = (unsigned long long*)(ws + W_CKEY);
    const bool ps = (ws_size >= (size_t)W_END_PS * 4);   // call-invariant -> graph-safe

    k0w<<<589824 / 256, 256, 0, stream>>>(conv_w, gw2);
    if (ps) {
        k0x<<<dim3(16, 16, 4), 256, 0, stream>>>(x, xsp);
        k1_mfma<true><<<dim3(32, 4, 4), 256, 0, stream>>>(x, xsp, gw2, conv_b, ws + W_H);
    } else {
        k1_mfma<false><<<dim3(32, 4, 4), 256, 0, stream>>>(x, nullptr, gw2, conv_b, ws + W_H);
    }
    k2_conv1<<<dim3(64, 4), 256, 0, stream>>>(ws + W_H, score_w, score_b, loc_w, loc_b, out,
                                              gh0, gcnt);
    k3_prop<<<dim3(144, 4), 256, 0, stream>>>(out, ws + W_R4, ws + W_SK, gh0);
    k4cut0<<<BATCH, 256, 0, stream>>>(gh0, ct0, pv0);
    k4cmp<<<dim3(32, BATCH), 256, 0, stream>>>(ws + W_SK, ct0, gcnt, ckey,
                                               ws + W_RS, (int*)(ws + W_VS));
    k4d_rank<<<dim3(144, BATCH), 256, 0, stream>>>(gcnt, ckey, ws + W_R4, ws + W_RS,
                                                   (int*)(ws + W_VS));
    k5_mat<<<dim3(NW, BATCH), 256, 0, stream>>>(ws + W_RS, (unsigned long long*)(ws + W_MAT));
    k5_scan<<<BATCH, 64, 0, stream>>>((const unsigned long long*)(ws + W_MAT),
                                      ws + W_RS, (const int*)(ws + W_VS), out);
}

// Round 9
// 828.755 us; speedup vs baseline: 1.3141x; 1.3141x over previous
//
#include <hip/hip_runtime.h>
#include <cstdint>
#include <cmath>

// ---------------- constants ----------------
namespace {
constexpr int BATCH = 4;
constexpr int CIN   = 512;
constexpr int CMID  = 512;
constexpr int HSZ   = 64, WSZ = 64, HWP = 4096;
constexpr int NA    = 36864;          // HW * 9 anchors
constexpr int NIN_  = 6000;
constexpr int NOUT2 = 300;
constexpr int NW    = 94;             // ceil(6000/64) u64 words per bitmask row

// d_out layout (float offsets)
constexpr size_t O_SC  = 0;           // rpn_scores (4,36864,2)
constexpr size_t O_LC  = 294912;      // rpn_locs   (4,36864,4)
constexpr size_t O_ROI = 884736;      // rois       (1200,4)
constexpr size_t O_IDX = 889536;      // roi_indices(1200)
constexpr size_t O_ANC = 890736;      // anchors    (36864,4)

// d_ws layout (float offsets).
// Aliasing rules:
//  - region [0, 8388608) is h; buffers there may be WRITTEN only after k2 (last h reader).
//  - region [8388608, 10747904) is gw2 (W fragments); DEAD after k1. gh0/gh1/gcnt live
//    there and are zeroed inside k2 (k2 never touches this region; k1 has completed) —
//    proven race-free in round 8. NOT the round-4 race (that zeroed h-aliased memory
//    while k2 blocks still read h).
// Level-1 radix refinement RESTORED (round-8 lesson: fg clusters near 0.5 -> the 12-bit
// level-0 cut bucket holds ~30k keys; one-level C ~ 36k made O(C^2) k4d cost 394 us).
constexpr size_t W_H    = 0;          // 8388608 floats (conv hidden, NCHW)
constexpr size_t W_WHI  = 8388608;    // 4718592 f16 W fragments [chunk][kk][cg][wc][nt][hl][lane][8]
constexpr size_t W_GH0  = 8388608;    // 16384 ints level-0 histogram (aliases gw2, dead post-k1)
constexpr size_t W_GH1  = 8404992;    // 16384 ints level-1 histogram (aliases gw2)
constexpr size_t W_GCNT = 8421376;    // 4 ints compact counter (aliases gw2)
constexpr size_t W_XSP  = 10747904;   // 16777216 f16 X split [b][chunk][px][ciq(hi4,lo4)]
constexpr size_t W_END_PS = 19136512; // high-water (floats) when x-split enabled
constexpr size_t W_R4   = 0;          // 589824  rois per anchor (aliases h)
constexpr size_t W_SK   = 589824;     // 147456  score keys (fg or -inf) -> ends 737280
constexpr size_t W_CT0  = 786496;     // 4 ints cut0 | 4 ints prev0 | 4 ints cut1
constexpr size_t W_CKEY = 901184;     // 147456 u64 keys (8B aligned)
constexpr size_t W_RS   = 1196096;    // 96000  sorted rois (4,6000,4)
constexpr size_t W_VS   = 1292096;    // 24000 ints sorted validity
constexpr size_t W_MAT  = 1316096;    // 4*6000*94 u64 (suppression bits)
} // namespace

typedef _Float16 f16;
typedef __attribute__((ext_vector_type(4))) _Float16 f16x4;
typedef __attribute__((ext_vector_type(8))) _Float16 f16x8;
typedef __attribute__((ext_vector_type(4))) float f32x4;

// ---------------- K0w: split conv_w*64 into f16 hi/lo, emit per-wave FRAGMENT layout ----
__global__ __launch_bounds__(256) void k0w(const float* __restrict__ w,
                                           f16* __restrict__ gw2) {
    int g = blockIdx.x * 256 + threadIdx.x;   // 589824 groups of 8 f16
    int lane = g & 63;
    int t1 = g >> 6;
    int hl = t1 & 1;
    int nt = (t1 >> 1) & 3;
    int wc = (t1 >> 3) & 1;
    int cg = (t1 >> 4) & 3;
    int ck = t1 >> 6;                 // 0..143
    int kk = ck % 9;
    int chunk = ck / 9;
    int co  = cg * 128 + wc * 64 + nt * 16 + (lane & 15);
    int ci0 = chunk * 32 + (lane >> 4) * 8;
    f16x8 o;
#pragma unroll
    for (int e = 0; e < 8; ++e) {
        float f = w[((size_t)co * CIN + ci0 + e) * 9 + kk] * 64.0f;
        f16 hv = (f16)f;
        o[e] = hl ? (f16)((f - (float)hv) * 2048.0f) : hv;
    }
    *(f16x8*)&gw2[(size_t)g * 8] = o;
}

// ---------------- K0x: pre-split X into f16 hi/lo, layout [b][chunk][px][ciq(hi4,lo4)] ----
__global__ __launch_bounds__(256) void k0x(const float* __restrict__ x,
                                           f16* __restrict__ xsp) {
    const int pt = blockIdx.x, ch = blockIdx.y, b = blockIdx.z, t = threadIdx.x;
    __shared__ float ld[32 * 261];   // [ci][px] pad 261 (odd) -> conflict-free column reads
    const int px0 = pt * 256;
    const int lpx = (t & 63) * 4, lc0 = t >> 6;
#pragma unroll
    for (int r = 0; r < 8; ++r) {
        int ci = r * 4 + lc0;
        float4 v = *(const float4*)&x[((size_t)(b * 512 + ch * 32 + ci)) * 4096 + px0 + lpx];
        float* d = &ld[ci * 261 + lpx];
        d[0] = v.x; d[1] = v.y; d[2] = v.z; d[3] = v.w;
    }
    __syncthreads();
    size_t ob = ((size_t)(b * 16 + ch) * 4096 + px0 + t) * 64;
#pragma unroll
    for (int cqx = 0; cqx < 8; ++cqx) {
        f16x8 o;
#pragma unroll
        for (int i = 0; i < 4; ++i) {
            float f = ld[(cqx * 4 + i) * 261 + t];
            f16 hf = (f16)f;
            o[i]     = hf;
            o[4 + i] = (f16)((f - (float)hf) * 2048.0f);
        }
        *(f16x8*)&xsp[ob + cqx * 8] = o;
    }
}

// ---------------- K1: 3x3 conv + bias + ReLU via f16-split MFMA (3 products) ----------
// Round-5 proven version (212 us).
template <bool PS>
__global__ __launch_bounds__(256, 2) void k1_mfma(const float* __restrict__ x,
                                                  const f16* __restrict__ xsp,
                                                  const f16* __restrict__ gw2,
                                                  const float* __restrict__ bias,
                                                  float* __restrict__ h) {
    const int pt = blockIdx.x, cg = blockIdx.y, b = blockIdx.z;
    const int y0 = pt * 2, co0 = cg * 128;
    const int t = threadIdx.x;
    const int wave = t >> 6, lane = t & 63;
    const int wp = wave >> 1, wc = wave & 1;   // px-half, co-half
    const int m = lane & 15, q = lane >> 4;

    __shared__ __align__(16) f16 xs[2][4 * 66 * 40];

    f32x4 acc1[2][2][4], acc2[2][2][4];
#pragma unroll
    for (int r = 0; r < 2; ++r)
#pragma unroll
        for (int j = 0; j < 2; ++j)
#pragma unroll
            for (int n = 0; n < 4; ++n) { acc1[r][j][n] = (f32x4)0.0f; acc2[r][j][n] = (f32x4)0.0f; }

    const int cq = t & 7, srow = (t >> 3) & 3, cseg = t >> 5;
    const int gy = y0 - 1 + srow;
    const bool yok = (gy >= 0 && gy < HSZ);

    if (t < 128) {   // zero borders (cols 0 and 65) of both planes, once
        int buf = t >> 6, rr = (t >> 4) & 3, cc = ((t >> 3) & 1) ? 65 : 0, cq2 = t & 7;
        f16x4 z = (f16x4)(f16)0.0f;
        *(f16x4*)&xs[buf][(rr * 66 + cc) * 40 + cq2 * 4] = z;
    }

    const size_t wlanebase = (size_t)(cg * 2 + wc) * 4096 + (size_t)lane * 8;

    for (int chunk = 0; chunk < 16; ++chunk) {
        __syncthreads();   // all waves done reading previous chunk's xs
        if (PS) {
            const f16* xb = xsp + (((size_t)(b * 16 + chunk) * 4096 + (size_t)(yok ? gy : 0) * 64) * 64);
#pragma unroll
            for (int jj = 0; jj < 8; ++jj) {
                int c = (jj + cq) & 7;
                int col = cseg * 8 + c + 1;
                f16x8 v = (f16x8)(f16)0.0f;
                if (yok) v = *(const f16x8*)&xb[(size_t)(cseg * 8 + c) * 64 + cq * 8];
                int base = (srow * 66 + col) * 40 + cq * 4;
                *(f16x4*)&xs[0][base] = __builtin_shufflevector(v, v, 0, 1, 2, 3);
                *(f16x4*)&xs[1][base] = __builtin_shufflevector(v, v, 4, 5, 6, 7);
            }
        } else {
            float vbuf[4][8];
            const float* xp = x + ((size_t)(b * CIN + chunk * 32 + cq * 4)) * HWP + gy * WSZ + cseg * 8;
#pragma unroll
            for (int i = 0; i < 4; ++i) {
                if (yok) {
                    float4 u0 = *(const float4*)(xp + (size_t)i * HWP);
                    float4 u1 = *(const float4*)(xp + (size_t)i * HWP + 4);
                    vbuf[i][0] = u0.x; vbuf[i][1] = u0.y; vbuf[i][2] = u0.z; vbuf[i][3] = u0.w;
                    vbuf[i][4] = u1.x; vbuf[i][5] = u1.y; vbuf[i][6] = u1.z; vbuf[i][7] = u1.w;
                } else {
#pragma unroll
                    for (int jj = 0; jj < 8; ++jj) vbuf[i][jj] = 0.0f;
                }
            }
#pragma unroll
            for (int jj = 0; jj < 8; ++jj) {
                int c = (jj + cq) & 7;
                int col = cseg * 8 + c + 1;
                f16x4 hv, lv;
#pragma unroll
                for (int i = 0; i < 4; ++i) {
                    float f = vbuf[i][c];
                    f16 hf = (f16)f;
                    hv[i] = hf;
                    lv[i] = (f16)((f - (float)hf) * 2048.0f);
                }
                int base = (srow * 66 + col) * 40 + cq * 4;
                *(f16x4*)&xs[0][base] = hv;
                *(f16x4*)&xs[1][base] = lv;
            }
        }
        __syncthreads();   // xs ready

        const f16* wck = gw2 + (size_t)chunk * (9 * 32768) + wlanebase;
#pragma unroll
        for (int kk = 0; kk < 9; ++kk) {
            const int ky = (kk >= 6) ? 2 : (kk >= 3) ? 1 : 0;
            const int kx = kk - ky * 3;
            const f16* wptr = wck + (size_t)kk * 32768;
            f16x8 bh[4], bl[4];
#pragma unroll
            for (int nt = 0; nt < 4; ++nt) {
                bh[nt] = *(const f16x8*)&wptr[nt * 1024];
                bl[nt] = *(const f16x8*)&wptr[nt * 1024 + 512];
            }
            f16x8 ah[2][2], al[2][2];
#pragma unroll
            for (int r = 0; r < 2; ++r)
#pragma unroll
                for (int j = 0; j < 2; ++j) {
                    int off = ((r + ky) * 66 + (wp * 2 + j) * 16 + m + kx) * 40 + q * 8;
                    ah[r][j] = *(const f16x8*)&xs[0][off];
                    al[r][j] = *(const f16x8*)&xs[1][off];
                }
#pragma unroll
            for (int r = 0; r < 2; ++r)
#pragma unroll
                for (int j = 0; j < 2; ++j)
#pragma unroll
                    for (int nt = 0; nt < 4; ++nt) {
                        acc1[r][j][nt] = __builtin_amdgcn_mfma_f32_16x16x32_f16(ah[r][j], bh[nt], acc1[r][j][nt], 0, 0, 0);
                        acc2[r][j][nt] = __builtin_amdgcn_mfma_f32_16x16x32_f16(ah[r][j], bl[nt], acc2[r][j][nt], 0, 0, 0);
                        acc2[r][j][nt] = __builtin_amdgcn_mfma_f32_16x16x32_f16(al[r][j], bh[nt], acc2[r][j][nt], 0, 0, 0);
                    }
        }
    }

#pragma unroll
    for (int r = 0; r < 2; ++r) {
        const int y = y0 + r;
#pragma unroll
        for (int nt = 0; nt < 4; ++nt) {
            const int co = co0 + wc * 64 + nt * 16 + m;
            const float bv = bias[co];
            size_t rowbase = ((size_t)(b * CMID + co)) * HWP + y * WSZ;
#pragma unroll
            for (int j = 0; j < 2; ++j) {
                float4 o;
                o.x = fmaxf((acc1[r][j][nt][0] + acc2[r][j][nt][0] * (1.0f / 2048.0f)) * (1.0f / 64.0f) + bv, 0.0f);
                o.y = fmaxf((acc1[r][j][nt][1] + acc2[r][j][nt][1] * (1.0f / 2048.0f)) * (1.0f / 64.0f) + bv, 0.0f);
                o.z = fmaxf((acc1[r][j][nt][2] + acc2[r][j][nt][2] * (1.0f / 2048.0f)) * (1.0f / 64.0f) + bv, 0.0f);
                o.w = fmaxf((acc1[r][j][nt][3] + acc2[r][j][nt][3] * (1.0f / 2048.0f)) * (1.0f / 64.0f) + bv, 0.0f);
                *(float4*)&h[rowbase + (wp * 2 + j) * 16 + q * 4] = o;
            }
        }
    }
}

// ---------------- K2: 1x1 convs (score 18 + loc 36) -> d_out; zeros gh0/gh1/gcnt -------
// gh0/gh1/gcnt alias the gw2 region (dead after k1, untouched by k2's own reads/writes)
// — zeroing here proven race-free in round 8.
__global__ __launch_bounds__(256) void k2_conv1(const float* __restrict__ h,
                                                const float* __restrict__ sw,
                                                const float* __restrict__ sb,
                                                const float* __restrict__ lw,
                                                const float* __restrict__ lb,
                                                float* __restrict__ out,
                                                int* __restrict__ gz,
                                                int* __restrict__ gcnt) {
    const int y = blockIdx.x;
    const int b = blockIdx.y;
    const int t = threadIdx.x;
    {
        int fb = (blockIdx.y * 64 + blockIdx.x) * 256 + t;   // 65536 threads
        if (fb < 2 * 4096 * BATCH) gz[fb] = 0;               // gh0 + gh1 (contiguous)
        if (fb < BATCH) gcnt[fb] = 0;
    }
    const int c4  = (t & 15) * 4;
    const int px4 = (t >> 4) * 4;
    __shared__ __align__(16) float hs[1024];
    __shared__ __align__(16) float wsm[16 * 68];

    float acc[4][4];
#pragma unroll
    for (int i = 0; i < 4; ++i)
#pragma unroll
        for (int j = 0; j < 4; ++j) acc[i][j] = 0.f;

    const int s_px = (t & 15) * 4;
    const int s_ci = t >> 4;
    for (int ci0 = 0; ci0 < CMID; ci0 += 16) {
        *(float4*)&hs[s_ci * 64 + s_px] =
            *(const float4*)&h[((size_t)(b * CMID + ci0 + s_ci)) * HWP + y * 64 + s_px];
#pragma unroll
        for (int k = 0; k < 4; ++k) {
            int idx = k * 256 + t;
            int ci = idx & 15, c = idx >> 4;
            float v = 0.f;
            if (c < 18) v = sw[c * 512 + ci0 + ci];
            else if (c < 54) v = lw[(c - 18) * 512 + ci0 + ci];
            wsm[ci * 68 + c] = v;
        }
        __syncthreads();
#pragma unroll
        for (int ci = 0; ci < 16; ++ci) {
            float4 hv = *(const float4*)&hs[ci * 64 + px4];
            float4 wv = *(const float4*)&wsm[ci * 68 + c4];
            acc[0][0] = fmaf(wv.x, hv.x, acc[0][0]);
            acc[0][1] = fmaf(wv.x, hv.y, acc[0][1]);
            acc[0][2] = fmaf(wv.x, hv.z, acc[0][2]);
            acc[0][3] = fmaf(wv.x, hv.w, acc[0][3]);
            acc[1][0] = fmaf(wv.y, hv.x, acc[1][0]);
            acc[1][1] = fmaf(wv.y, hv.y, acc[1][1]);
            acc[1][2] = fmaf(wv.y, hv.z, acc[1][2]);
            acc[1][3] = fmaf(wv.y, hv.w, acc[1][3]);
            acc[2][0] = fmaf(wv.z, hv.x, acc[2][0]);
            acc[2][1] = fmaf(wv.z, hv.y, acc[2][1]);
            acc[2][2] = fmaf(wv.z, hv.z, acc[2][2]);
            acc[2][3] = fmaf(wv.z, hv.w, acc[2][3]);
            acc[3][0] = fmaf(wv.w, hv.x, acc[3][0]);
            acc[3][1] = fmaf(wv.w, hv.y, acc[3][1]);
            acc[3][2] = fmaf(wv.w, hv.z, acc[3][2]);
            acc[3][3] = fmaf(wv.w, hv.w, acc[3][3]);
        }
        __syncthreads();
    }

#pragma unroll
    for (int cc = 0; cc < 4; ++cc) {
        int c = c4 + cc;
        if (c >= 54) break;
        float bv = (c < 18) ? sb[c] : lb[c - 18];
#pragma unroll
        for (int pp = 0; pp < 4; ++pp) {
            int px = y * 64 + px4 + pp;
            float v = acc[cc][pp] + bv;
            if (c < 18)
                out[O_SC + (size_t)b * 73728 + (size_t)px * 18 + c] = v;
            else
                out[O_LC + (size_t)b * 147456 + (size_t)px * 36 + (c - 18)] = v;
        }
    }
}

// ---------------- K3: anchors + softmax-fg + loc2bbox + clip + level-0 histogram -------
__global__ __launch_bounds__(256) void k3_prop(float* __restrict__ out,
                                               float* __restrict__ rois4,
                                               float* __restrict__ skey,
                                               int* __restrict__ gh0) {
    const int t = threadIdx.x;
    const int p = blockIdx.x * 256 + t;
    const int b = blockIdx.y;
    __shared__ int lh[4096];
    for (int k = t; k < 4096; k += 256) lh[k] = 0;
    __syncthreads();
    const int px = p / 9;
    const int a  = p - px * 9;
    const int yy = px >> 6, xx = px & 63;
    const int ri = a / 3, si = a - ri * 3;
    const double rat[3] = {0.5, 1.0, 2.0};
    const double scl[3] = {8.0, 16.0, 32.0};
    double hhd = 16.0 * scl[si] * sqrt(rat[ri]);
    double wwd = 16.0 * scl[si] * sqrt(1.0 / rat[ri]);
    float a0 = (float)(8.0 - hhd / 2.0), a1 = (float)(8.0 - wwd / 2.0);
    float a2 = (float)(8.0 + hhd / 2.0), a3 = (float)(8.0 + wwd / 2.0);
    float sy = (float)(yy * 16), sx = (float)(xx * 16);
    float A0 = sy + a0, A1 = sx + a1, A2 = sy + a2, A3 = sx + a3;
    if (b == 0) {
        float4 av; av.x = A0; av.y = A1; av.z = A2; av.w = A3;
        *(float4*)&out[O_ANC + (size_t)p * 4] = av;
    }
    const float* sc = out + O_SC + (size_t)b * 73728 + (size_t)px * 18 + a * 2;
    float s0 = sc[0], s1 = sc[1];
    float mm = fmaxf(s0, s1);
    float e0 = expf(s0 - mm), e1 = expf(s1 - mm);
    float fg = e1 / (e0 + e1);
    const float* lc = out + O_LC + (size_t)b * 147456 + (size_t)px * 36 + a * 4;
    float dy = lc[0], dxv = lc[1], dh = lc[2], dwv = lc[3];
    float ah = A2 - A0, aw = A3 - A1;
    float cy = A0 + 0.5f * ah, cx = A1 + 0.5f * aw;
    float cty = dy * ah + cy, ctx = dxv * aw + cx;
    float th = expf(dh) * ah, tw = expf(dwv) * aw;
    float ry1 = cty - 0.5f * th, rx1 = ctx - 0.5f * tw;
    float ry2 = cty + 0.5f * th, rx2 = ctx + 0.5f * tw;
    float y1 = fminf(fmaxf(ry1, 0.f), 1024.f);
    float y2 = fminf(fmaxf(ry2, 0.f), 1024.f);
    float x1 = fminf(fmaxf(rx1, 0.f), 1024.f);
    float x2 = fminf(fmaxf(rx2, 0.f), 1024.f);
    bool valid = ((y2 - y1) >= 16.f) && ((x2 - x1) >= 16.f);
    float sk = valid ? fg : -__builtin_inff();
    float4 rv; rv.x = y1; rv.y = x1; rv.z = y2; rv.w = x2;
    *(float4*)&rois4[((size_t)b * NA + p) * 4] = rv;
    skey[(size_t)b * NA + p] = sk;
    // level-0 histogram of the sortable key's top 12 bits
    unsigned uu = __float_as_uint(sk);
    uu = (uu & 0x80000000u) ? ~uu : (uu | 0x80000000u);
    atomicAdd(&lh[uu >> 20], 1);
    __syncthreads();
    for (int k = t; k < 4096; k += 256) {
        int v = lh[k];
        if (v) atomicAdd(&gh0[(size_t)b * 4096 + k], v);
    }
}

// ---------------- K4a: level-0 cut from gh0 (grid=BATCH) ----------------
__global__ __launch_bounds__(256) void k4cut0(const int* __restrict__ gh,
                                              int* __restrict__ cut0,
                                              int* __restrict__ prev0) {
    const int b = blockIdx.x, t = threadIdx.x;
    __shared__ int hh[4096];
    __shared__ int tsum[256];
    __shared__ int s_cut, s_prev;
    for (int k = t; k < 4096; k += 256) hh[k] = gh[(size_t)b * 4096 + k];
    __syncthreads();
    int s = 0;
#pragma unroll
    for (int j = 0; j < 16; ++j) s += hh[t * 16 + j];
    tsum[t] = s;
    __syncthreads();
    if (t == 0) {
        int run = 0;
        for (int tt = 255; tt >= 0; --tt) { int tmp = tsum[tt]; tsum[tt] = run; run += tmp; }
    }
    __syncthreads();
    {
        const int target = NIN_;
        int run = tsum[t];
        for (int v = t * 16 + 15; v >= t * 16; --v) {
            int prev = run;
            run += hh[v];
            if (run >= target && prev < target) { s_cut = v; s_prev = prev; }
        }
    }
    __syncthreads();
    if (t == 0) { cut0[b] = s_cut; prev0[b] = s_prev; }
}

// ---------------- K4b: parallel level-1 histogram (grid=(32,BATCH)); also prefills
// rois_s/valid_s with zeros (insurance; h is dead by now) ----------------
__global__ __launch_bounds__(256) void k4h1(const float* __restrict__ skey,
                                            const int* __restrict__ cut0,
                                            int* __restrict__ gh1,
                                            float* __restrict__ rois_s,
                                            int* __restrict__ valid_s) {
    const int b = blockIdx.y, t = threadIdx.x;
    {
        int gid = (blockIdx.y * 32 + blockIdx.x) * 256 + t;   // 0..32767
        if (gid < BATCH * NIN_) valid_s[gid] = 0;
        for (int k = gid; k < BATCH * NIN_ * 4; k += 32768) rois_s[k] = 0.f;
    }
    __shared__ int lh[4096];
    for (int k = t; k < 4096; k += 256) lh[k] = 0;
    __syncthreads();
    const int c1 = cut0[b];
    for (int i = blockIdx.x * 256 + t; i < NA; i += 32 * 256) {
        float sk = skey[(size_t)b * NA + i];
        unsigned u = __float_as_uint(sk);
        u = (u & 0x80000000u) ? ~u : (u | 0x80000000u);
        if ((int)(u >> 20) == c1) atomicAdd(&lh[(u >> 8) & 0xFFFu], 1);
    }
    __syncthreads();
    for (int k = t; k < 4096; k += 256) {
        int v = lh[k];
        if (v) atomicAdd(&gh1[(size_t)b * 4096 + k], v);
    }
}

// ---------------- K4c: level-1 cut from gh1 (grid=BATCH) ----------------
__global__ __launch_bounds__(256) void k4cut1(const int* __restrict__ gh,
                                              const int* __restrict__ prev0,
                                              int* __restrict__ cut1) {
    const int b = blockIdx.x, t = threadIdx.x;
    __shared__ int hh[4096];
    __shared__ int tsum[256];
    __shared__ int s_cut;
    for (int k = t; k < 4096; k += 256) hh[k] = gh[(size_t)b * 4096 + k];
    __syncthreads();
    int s = 0;
#pragma unroll
    for (int j = 0; j < 16; ++j) s += hh[t * 16 + j];
    tsum[t] = s;
    __syncthreads();
    if (t == 0) {
        int run = 0;
        for (int tt = 255; tt >= 0; --tt) { int tmp = tsum[tt]; tsum[tt] = run; run += tmp; }
    }
    __syncthreads();
    {
        const int target = NIN_ - prev0[b];
        int run = tsum[t];
        for (int v = t * 16 + 15; v >= t * 16; --v) {
            int prev = run;
            run += hh[v];
            if (run >= target && prev < target) { s_cut = v; }
        }
    }
    __syncthreads();
    if (t == 0) cut1[b] = s_cut;
}

// ---------------- K4e: parallel compaction (grid=(32,BATCH)), block-aggregated ----------
// take = 24-bit prefix >= (cut0,cut1). C in [6000, ~6016); k4d's exact counting-rank
// emits precisely the global top-6000 (non-candidates all have strictly smaller keys).
__global__ __launch_bounds__(256) void k4cmp(const float* __restrict__ skey,
                                             const int* __restrict__ cut0,
                                             const int* __restrict__ cut1,
                                             int* __restrict__ gcnt,
                                             unsigned long long* __restrict__ ckey) {
    const int b = blockIdx.y, t = threadIdx.x;
    __shared__ unsigned long long lbuf[1280];
    __shared__ int lcnt, lbase;
    if (t == 0) lcnt = 0;
    __syncthreads();
    const int c1 = cut0[b], c2 = cut1[b];
    for (int i = blockIdx.x * 256 + t; i < NA; i += 32 * 256) {
        float sk = skey[(size_t)b * NA + i];
        unsigned u = __float_as_uint(sk);
        u = (u & 0x80000000u) ? ~u : (u | 0x80000000u);
        int b1 = (int)(u >> 20), b2 = (int)((u >> 8) & 0xFFFu);
        if (b1 > c1 || (b1 == c1 && b2 >= c2)) {
            int lp = atomicAdd(&lcnt, 1);
            lbuf[lp] = ((unsigned long long)u << 16) | (unsigned long long)(36863 - i);
        }
    }
    __syncthreads();
    if (t == 0) lbase = atomicAdd(gcnt + b, lcnt);
    __syncthreads();
    const int n = lcnt, base = lbase;
    for (int k = t; k < n; k += 256) ckey[(size_t)b * NA + base + k] = lbuf[k];
}

// ---------------- K4d: counting-rank over compacted keys, emit top-6000 ------
__global__ __launch_bounds__(256) void k4d_rank(const int* __restrict__ cnt,
                                                const unsigned long long* __restrict__ ckey,
                                                const float* __restrict__ rois4,
                                                float* __restrict__ rois_s,
                                                int* __restrict__ valid_s) {
    const int b = blockIdx.y;
    const int C = cnt[b];
    if (blockIdx.x * 256 >= C) return;
    const int gi = blockIdx.x * 256 + threadIdx.x;
    const bool act = gi < C;
    const unsigned long long mk = act ? ckey[(size_t)b * NA + gi] : 0ULL;
    __shared__ unsigned long long kl[512];
    int rank = 0;
    for (int c0 = 0; c0 < C; c0 += 512) {
        __syncthreads();
#pragma unroll
        for (int kk = 0; kk < 2; ++kk) {
            int k = threadIdx.x + kk * 256;
            int src = c0 + k;
            kl[k] = (src < C) ? ckey[(size_t)b * NA + src] : 0ULL;
        }
        __syncthreads();
        if (act) {
            int n = min(512, C - c0);
            int j = 0;
            for (; j + 4 <= n; j += 4) {
                rank += (kl[j]     > mk);
                rank += (kl[j + 1] > mk);
                rank += (kl[j + 2] > mk);
                rank += (kl[j + 3] > mk);
            }
            for (; j < n; ++j) rank += (kl[j] > mk);
        }
    }
    if (act && rank < NIN_) {
        int p = 36863 - (int)(mk & 0xFFFFull);
        const float4 bx = *(const float4*)&rois4[((size_t)b * NA + p) * 4];
        *(float4*)&rois_s[((size_t)b * NIN_ + rank) * 4] = bx;
        valid_s[b * NIN_ + rank] = ((unsigned)(mk >> 16) != 0x007FFFFFu) ? 1 : 0;
    }
}

// ---------------- K5a: pairwise suppression bitmask matrix ----------------
__global__ __launch_bounds__(256) void k5_mat(const float* __restrict__ rois_s,
                                              unsigned long long* __restrict__ mat) {
    const int b = blockIdx.y, rb = blockIdx.x;
    const int t = threadIdx.x, wave = t >> 6, lane = t & 63;
    const int i = rb * 64 + lane;
    const bool rowok = (i < NIN_);
    __shared__ float cs[4][5][64];
    const float* bb = rois_s + (size_t)b * NIN_ * 4;

    float r0 = 0, r1 = 0, r2 = 0, r3 = 0, ra = 0;
    if (rowok) {
        float4 v = *(const float4*)&bb[(size_t)i * 4];
        r0 = v.x; r1 = v.y; r2 = v.z; r3 = v.w;
        ra = (v.z - v.x) * (v.w - v.y);
    }
    unsigned long long* mrow = mat + ((size_t)b * NIN_ + (size_t)(rowok ? i : 0)) * NW;

    if (rowok)
        for (int cb = wave; cb < rb; cb += 4) mrow[cb] = 0ull;

    for (int cb = rb + wave; cb < NW; cb += 4) {
        const int j0 = cb * 64;
        const int j  = j0 + lane;
        float4 v;
        if (j < NIN_) v = *(const float4*)&bb[(size_t)j * 4];
        else { v.x = 0; v.y = 0; v.z = 0; v.w = 0; }
        cs[wave][0][lane] = v.x; cs[wave][1][lane] = v.y;
        cs[wave][2][lane] = v.z; cs[wave][3][lane] = v.w;
        cs[wave][4][lane] = (v.z - v.x) * (v.w - v.y);
        unsigned long long wm = 0;
        if (rowok) {
#pragma unroll 8
            for (int k = 0; k < 64; ++k) {
                float yy1 = fmaxf(r0, cs[wave][0][k]), xx1 = fmaxf(r1, cs[wave][1][k]);
                float yy2 = fminf(r2, cs[wave][2][k]), xx2 = fminf(r3, cs[wave][3][k]);
                float inter = fmaxf(yy2 - yy1, 0.f) * fmaxf(xx2 - xx1, 0.f);
                float iou = inter / (ra + cs[wave][4][k] - inter + 1e-9f);
                int jj = j0 + k;
                if ((iou > 0.7f) && (jj > i) && (jj < NIN_)) wm |= (1ull << k);
            }
            mrow[cb] = wm;
        }
    }
}

// ---------------- K5b: serial greedy scan, PAIRED candidate processing (proven r7) ------
__global__ __launch_bounds__(64) void k5_scan(const unsigned long long* __restrict__ mat,
                                              const float* __restrict__ rois_s,
                                              const int* __restrict__ valid_s,
                                              float* __restrict__ out) {
    const int b = blockIdx.x, t = threadIdx.x;
    for (int k = t; k < NOUT2 * 4; k += 64) out[O_ROI + (size_t)b * NOUT2 * 4 + k] = 0.f;
    for (int k = t; k < NOUT2; k += 64) out[O_IDX + (size_t)b * NOUT2 + k] = (float)b;

    unsigned long long A = 0, B = 0;
    for (int w = 0; w < NW; ++w) {
        int i = w * 64 + t;
        int v = (i < NIN_) ? valid_s[b * NIN_ + i] : 0;
        unsigned long long m = __ballot(v == 0);
        if (w < 64) { if (t == w) A = m; }
        else        { if (t == w - 64) B = m; }
    }

    const unsigned long long* mb = mat + (size_t)b * NIN_ * NW;
    const float* bb = rois_s + (size_t)b * NIN_ * 4;
    int kept = 0;
    for (int w = 0; w < NW && kept < NOUT2; ++w) {
        unsigned long long cur = (w < 64) ? __shfl(A, w) : __shfl(B, w - 64);
        unsigned long long avail = ~cur;
        while (avail != 0ull && kept < NOUT2) {
            int b0 = __builtin_ctzll(avail);
            unsigned long long rest = avail & (avail - 1ull);
            const int i0 = w * 64 + b0;
            const unsigned long long* row0 = mb + (size_t)i0 * NW;
            unsigned long long r0A = row0[t];
            unsigned long long r0B = (t < NW - 64) ? row0[64 + t] : 0ull;
            const bool has1 = (rest != 0ull);
            const int b1 = has1 ? __builtin_ctzll(rest) : 0;
            unsigned long long r1A = 0ull, r1B = 0ull;
            if (has1) {
                const unsigned long long* row1 = mb + (size_t)(w * 64 + b1) * NW;
                r1A = row1[t];
                r1B = (t < NW - 64) ? row1[64 + t] : 0ull;
            }
            if (t == 0) {
                float4 bx = *(const float4*)&bb[(size_t)i0 * 4];
                *(float4*)&out[O_ROI + ((size_t)b * NOUT2 + kept) * 4] = bx;
            }
            kept++;
            if (kept >= NOUT2) break;
            A |= r0A; B |= r0B;
            unsigned long long rw0 = (w < 64) ? __shfl(r0A, w) : __shfl(r0B, w - 64);
            avail &= ~rw0;
            avail &= ~(1ull << b0);
            if (has1 && (avail & (1ull << b1))) {
                // b1 survived row0 (and all earlier rows) -> it IS the next kept box;
                // its row is already in registers.
                if (t == 0) {
                    float4 bx = *(const float4*)&bb[(size_t)(w * 64 + b1) * 4];
                    *(float4*)&out[O_ROI + ((size_t)b * NOUT2 + kept) * 4] = bx;
                }
                kept++;
                if (kept >= NOUT2) break;
                A |= r1A; B |= r1B;
                unsigned long long rw1 = (w < 64) ? __shfl(r1A, w) : __shfl(r1B, w - 64);
                avail &= ~rw1;
                avail &= ~(1ull << b1);
            }
        }
    }
}

// ---------------- launch ----------------
extern "C" void kernel_launch(void* const* d_in, const int* in_sizes, int n_in,
                              void* d_out, int out_size, void* d_ws, size_t ws_size,
                              hipStream_t stream) {
    const float* x       = (const float*)d_in[0];
    const float* conv_w  = (const float*)d_in[1];
    const float* conv_b  = (const float*)d_in[2];
    const float* score_w = (const float*)d_in[3];
    const float* score_b = (const float*)d_in[4];
    const float* loc_w   = (const float*)d_in[5];
    const float* loc_b   = (const float*)d_in[6];
    float* out = (float*)d_out;
    float* ws  = (float*)d_ws;

    f16* gw2 = (f16*)(ws + W_WHI);   // 4718592 f16 pre-swizzled W fragments
    f16* xsp = (f16*)(ws + W_XSP);
    int* gh0  = (int*)(ws + W_GH0);   // aliases gw2 (dead after k1); zeroed in k2
    int* gh1  = (int*)(ws + W_GH1);   // aliases gw2
    int* gcnt = (int*)(ws + W_GCNT);  // aliases gw2
    int* ct0  = (int*)(ws + W_CT0);
    int* pv0  = ct0 + BATCH;
    int* ct1  = pv0 + BATCH;
    unsigned long long* ckey = (unsigned long long*)(ws + W_CKEY);
    const bool ps = (ws_size >= (size_t)W_END_PS * 4);   // call-invariant -> graph-safe

    k0w<<<589824 / 256, 256, 0, stream>>>(conv_w, gw2);
    if (ps) {
        k0x<<<dim3(16, 16, 4), 256, 0, stream>>>(x, xsp);
        k1_mfma<true><<<dim3(32, 4, 4), 256, 0, stream>>>(x, xsp, gw2, conv_b, ws + W_H);
    } else {
        k1_mfma<false><<<dim3(32, 4, 4), 256, 0, stream>>>(x, nullptr, gw2, conv_b, ws + W_H);
    }
    k2_conv1<<<dim3(64, 4), 256, 0, stream>>>(ws + W_H, score_w, score_b, loc_w, loc_b, out,
                                              gh0, gcnt);
    k3_prop<<<dim3(144, 4), 256, 0, stream>>>(out, ws + W_R4, ws + W_SK, gh0);
    k4cut0<<<BATCH, 256, 0, stream>>>(gh0, ct0, pv0);
    k4h1<<<dim3(32, BATCH), 256, 0, stream>>>(ws + W_SK, ct0, gh1, ws + W_RS,
                                              (int*)(ws + W_VS));
    k4cut1<<<BATCH, 256, 0, stream>>>(gh1, pv0, ct1);
    k4cmp<<<dim3(32, BATCH), 256, 0, stream>>>(ws + W_SK, ct0, ct1, gcnt, ckey);
    k4d_rank<<<dim3(144, BATCH), 256, 0, stream>>>(gcnt, ckey, ws + W_R4, ws + W_RS,
                                                   (int*)(ws + W_VS));
    k5_mat<<<dim3(NW, BATCH), 256, 0, stream>>>(ws + W_RS, (unsigned long long*)(ws + W_MAT));
    k5_scan<<<BATCH, 64, 0, stream>>>((const unsigned long long*)(ws + W_MAT),
                                      ws + W_RS, (const int*)(ws + W_VS), out);
}